// Round 8
// baseline (3226.978 us; speedup 1.0000x reference)
//
#include <hip/hip_runtime.h>
#include <math.h>

#define NA      128
#define NBATCH  2048
#define NTHR    512
#define NELB    8       // one wave per element; 256 blocks -> 1 block/CU
#define NIT     300
#define NBIS    40      // full 40: NBIS=24 -> absmax 8e-3 (chaotic tau amplification)
#define LRC     0.02f
#define EPSC    1e-8f

// R15 theory: per-CU cost invariant ~2700 cy/element-iter across ALL layouts
// (R0/R3/R7) -> CU-shared cross-lane crossbar at ~4.8cy/op is the binder
// (~560 cross-lane ops/elem-iter: bisect 40x13 + reduce + minmax).
// This version cuts cross-lane to ~27/elem-iter BIT-EXACTLY:
//  - one WAVE per element (lane l owns rows 2l,2l+1): matvec+reduce+grad
//    barrier-free, part[] LDS gone, Aw in registers. Reduce leaf
//    w[2l]Aw[2l]+w[2l+1]Aw[2l+1] + the same 6-step DPP tree == old
//    wave0+wave1 tree (same association shape, commutations only).
//  - bisection: 8 elements x 8 lanes in ONE wave. Lane g computes subtree
//    S_g = ((t0+t1)+(t2+t3))+((t4+t5)+(t6+t7)) over its 8 leaves
//    sequentially, then XOR butterfly (quad_perm ^1, ^2, ds_swizzle ^4)
//    joins S0..S7 -- same tree shape as old shr8/bcast15/bcast31 levels
//    -> bit-identical sum in EVERY lane (no readlane/broadcast at all).
// fp contract: absmax must stay exactly 2.288818e-3.

// ---- wave64 canonical sum tree (UNCHANGED fp contract) ----
template <int CTRL>
__device__ __forceinline__ float dpp_sum_step(float x) {
  int s = __builtin_amdgcn_update_dpp(0, __float_as_int(x), CTRL, 0xF, 0xF, true);
  return x + __int_as_float(s);
}
__device__ __forceinline__ float wave_sum64(float x) {
  x = dpp_sum_step<0x111>(x);
  x = dpp_sum_step<0x112>(x);
  x = dpp_sum_step<0x114>(x);
  x = dpp_sum_step<0x118>(x);
  x = dpp_sum_step<0x142>(x);
  x = dpp_sum_step<0x143>(x);
  return x;  // total in lane 63
}
__device__ __forceinline__ float bcast63(float x) {
  return __int_as_float(__builtin_amdgcn_readlane(__float_as_int(x), 63));
}
// quad_perm move (xor1: 0xB1, xor2: 0x4E)
template <int CTRL>
__device__ __forceinline__ float dpp_qp(float x) {
  int s = __builtin_amdgcn_update_dpp(0, __float_as_int(x), CTRL, 0xF, 0xF, true);
  return __int_as_float(s);
}
// ds_swizzle xor4 (offset = (4<<10)|0x1F)
__device__ __forceinline__ float swz_xor4(float x) {
  int s = __builtin_amdgcn_ds_swizzle(__float_as_int(x), 0x101F);
  return __int_as_float(s);
}
__device__ __forceinline__ float clip1(float x) {
  return __builtin_amdgcn_fmed3f(x, -1.0f, 1.0f);  // c = MAX_WEIGHT = 1
}

__global__ __launch_bounds__(NTHR)
void markowitz_kernel(
    const float* __restrict__ rets,
    const float* __restrict__ covmat,
    const float* __restrict__ gamma,
    const float* __restrict__ alpha,
    float* __restrict__ out)
{
  const int b    = blockIdx.x;      // 0..255
  const int tid  = threadIdx.x;
  const int wv   = tid >> 6;        // wave = local element 0..7
  const int lane = tid & 63;
  const int e    = b * NELB + wv;   // global batch element
  const int r0   = 2 * lane;        // owned rows r0, r0+1

  __shared__ __align__(16) float ws[NELB][NA];  // weights
  __shared__ __align__(16) float vs[NELB][NA];  // pre-projection vector

  const float gm = gamma[e];
  const float av = fabsf(alpha[e]);
  const float* A0 = covmat + (size_t)e * NA * NA + (size_t)r0 * NA;
  const float2 rc = *reinterpret_cast<const float2*>(rets + (size_t)e * NA + r0);

  *reinterpret_cast<float2*>(&ws[wv][r0]) = make_float2(1.0f / NA, 1.0f / NA);
  __syncthreads();

#pragma unroll 1
  for (int it = 0; it < NIT; ++it) {
    // ---- 1. matvec rows r0, r0+1 (canonical per-quarter fp order) ----
    float qs0[4], qs1[4];
#pragma unroll
    for (int q = 0; q < 4; ++q) {
      const float4* a0 = reinterpret_cast<const float4*>(A0 + q * 32);
      const float4* a1 = reinterpret_cast<const float4*>(A0 + NA + q * 32);
      const float4* w4 = reinterpret_cast<const float4*>(ws[wv]) + q * 8;
      float4 c0 = make_float4(0.f, 0.f, 0.f, 0.f);
      float4 c1 = make_float4(0.f, 0.f, 0.f, 0.f);
#pragma unroll
      for (int k = 0; k < 8; ++k) {
        float4 wk = w4[k];  // wave-uniform LDS broadcast
        float4 t0 = a0[k];
        c0.x = fmaf(t0.x * gm, wk.x, c0.x);
        c0.y = fmaf(t0.y * gm, wk.y, c0.y);
        c0.z = fmaf(t0.z * gm, wk.z, c0.z);
        c0.w = fmaf(t0.w * gm, wk.w, c0.w);
        float4 t1 = a1[k];
        c1.x = fmaf(t1.x * gm, wk.x, c1.x);
        c1.y = fmaf(t1.y * gm, wk.y, c1.y);
        c1.z = fmaf(t1.z * gm, wk.z, c1.z);
        c1.w = fmaf(t1.w * gm, wk.w, c1.w);
      }
      qs0[q] = (c0.x + c0.y) + (c0.z + c0.w);
      qs1[q] = (c1.x + c1.y) + (c1.z + c1.w);
    }
    const float Aw0 = (qs0[0] + qs0[1]) + (qs0[2] + qs0[3]);
    const float Aw1 = (qs1[0] + qs1[1]) + (qs1[2] + qs1[3]);

    // ---- 2. in-wave reductions (leaf = pair of rows 2l,2l+1; tree shape
    //         == old wave0+wave1; asm pins stop mul+add->fma contraction) ----
    const float2 wp = *reinterpret_cast<const float2*>(&ws[wv][r0]);
    float p0 = wp.x * Aw0, p1 = wp.y * Aw1;
    asm volatile("" : "+v"(p0), "+v"(p1));
    float u0 = wp.x * wp.x, u1 = wp.y * wp.y;
    asm volatile("" : "+v"(u0), "+v"(u1));
    const float sAw = bcast63(wave_sum64(p0 + p1));
    const float sww = bcast63(wave_sum64(u0 + u1));

    // ---- 3. gradient step -> vs (expressions verbatim from verified kernel) ----
    const float risk = sqrtf(sAw + EPSC);
    const float nrm  = sqrtf(sww + EPSC);
    const float g0 = rc.x - Aw0 / risk - av * (wp.x / nrm);
    const float g1 = rc.y - Aw1 / risk - av * (wp.y / nrm);
    const float v0 = wp.x + LRC * g0;
    const float v1 = wp.y + LRC * g1;
    *reinterpret_cast<float2*>(&vs[wv][r0]) = make_float2(v0, v1);
    __syncthreads();

    // ---- 4. bisection: 8 elements x 8 lanes, one wave ----
    if (wv == 0) {
      const int be = lane >> 3;   // element
      const int gg = lane & 7;    // subtree slot: leaves J = 8g..8g+7
      float4 la = *reinterpret_cast<const float4*>(&vs[be][8 * gg]);
      float4 lb = *reinterpret_cast<const float4*>(&vs[be][8 * gg + 4]);
      float4 ha = *reinterpret_cast<const float4*>(&vs[be][64 + 8 * gg]);
      float4 hb = *reinterpret_cast<const float4*>(&vs[be][64 + 8 * gg + 4]);
      const float vlo[8] = {la.x, la.y, la.z, la.w, lb.x, lb.y, lb.z, lb.w};
      const float vhi[8] = {ha.x, ha.y, ha.z, ha.w, hb.x, hb.y, hb.z, hb.w};

      // min/max: exact ops, order-free
      float mn = fminf(vlo[0], vhi[0]);
      float mx = fmaxf(vlo[0], vhi[0]);
#pragma unroll
      for (int j = 1; j < 8; ++j) {
        mn = fminf(mn, fminf(vlo[j], vhi[j]));
        mx = fmaxf(mx, fmaxf(vlo[j], vhi[j]));
      }
      mn = fminf(mn, dpp_qp<0xB1>(mn));
      mn = fminf(mn, dpp_qp<0x4E>(mn));
      mn = fminf(mn, swz_xor4(mn));
      mx = fmaxf(mx, dpp_qp<0xB1>(mx));
      mx = fmaxf(mx, dpp_qp<0x4E>(mx));
      mx = fmaxf(mx, swz_xor4(mx));

      float lo = mn - 2.0f;   // min(v) - c - 1
      float hi = mx + 1.0f;   // max(v) + c
#pragma unroll 1
      for (int rr = 0; rr < NBIS; ++rr) {
        const float mid = 0.5f * (lo + hi);
        float t[8];
#pragma unroll
        for (int j = 0; j < 8; ++j)
          t[j] = clip1(vlo[j] - mid) + clip1(vhi[j] - mid);
        // canonical 8-leaf subtree (same shape as DPP shr1/shr2/shr4 levels)
        float s = ((t[0] + t[1]) + (t[2] + t[3])) + ((t[4] + t[5]) + (t[6] + t[7]));
        // butterfly join of S0..S7: same shapes as shr8/bcast15/bcast31
        s = s + dpp_qp<0xB1>(s);
        s = s + dpp_qp<0x4E>(s);
        s = s + swz_xor4(s);
        const bool big = s > 1.0f;
        lo = big ? mid : lo;
        hi = big ? hi : mid;
      }
      const float tau = 0.5f * (lo + hi);
      float4 o;
      o.x = clip1(vlo[0] - tau); o.y = clip1(vlo[1] - tau);
      o.z = clip1(vlo[2] - tau); o.w = clip1(vlo[3] - tau);
      *reinterpret_cast<float4*>(&ws[be][8 * gg]) = o;
      o.x = clip1(vlo[4] - tau); o.y = clip1(vlo[5] - tau);
      o.z = clip1(vlo[6] - tau); o.w = clip1(vlo[7] - tau);
      *reinterpret_cast<float4*>(&ws[be][8 * gg + 4]) = o;
      o.x = clip1(vhi[0] - tau); o.y = clip1(vhi[1] - tau);
      o.z = clip1(vhi[2] - tau); o.w = clip1(vhi[3] - tau);
      *reinterpret_cast<float4*>(&ws[be][64 + 8 * gg]) = o;
      o.x = clip1(vhi[4] - tau); o.y = clip1(vhi[5] - tau);
      o.z = clip1(vhi[6] - tau); o.w = clip1(vhi[7] - tau);
      *reinterpret_cast<float4*>(&ws[be][64 + 8 * gg + 4]) = o;
    }
    __syncthreads();
  }

  *reinterpret_cast<float2*>(out + (size_t)e * NA + r0) =
      make_float2(ws[wv][r0], ws[wv][r0 + 1]);
}

extern "C" void kernel_launch(void* const* d_in, const int* in_sizes, int n_in,
                              void* d_out, int out_size, void* d_ws, size_t ws_size,
                              hipStream_t stream) {
  const float* rets   = (const float*)d_in[0];
  const float* covmat = (const float*)d_in[1];
  const float* gamma  = (const float*)d_in[2];
  const float* alpha  = (const float*)d_in[3];
  float* out = (float*)d_out;

  hipLaunchKernelGGL(markowitz_kernel, dim3(NBATCH / NELB), dim3(NTHR), 0, stream,
                     rets, covmat, gamma, alpha, out);
}